// Round 24
// baseline (283.376 us; speedup 1.0000x reference)
//
#include <hip/hip_runtime.h>

// VectorQuantizer: B=16, T=4096, D=256, K=1024 (fp32 in/out)
// N = B*T = 65536. out[n] = codebook[argmin_k ||x_n - c_k||^2]
//
// Three-tier cascade, every tier a previously-PASSED numeric config:
//   T1) hi-only bf16 MFMA assign (R21..R23-verbatim, ~86us): 32-code tiles,
//       contiguous layout, 0 conflicts. gap < 0.3 -> flag (~10k pts).
//   T2) gathered 3-chain bf16 MFMA re-assign (R20-verbatim numerics,
//       err sigma~1e-4) -- R24: GLOBAL-DIRECT, no LDS, no barriers
//       (R23 lesson: LDS+barrier staging at 1 block/CU = full stall
//       exposure, 110us; coalesced 1KB wave loads from the permuted
//       global tiles free-run instead). gap < 8e-3 -> flag2 (~4 pts).
//   T3) fp64 ILP full scan (R19-verbatim) + tie rule "runner-up within
//       TIE_TOL=3.5e-5 and lower index wins" (round-6 verified).

#define DIMS   256
#define NCODE  1024
#define NPTS   65536
#define BMBLK  64           // points per block (4 waves x 16)
#define NT1    32           // tier-1: 32-code tiles
#define TB1    16384        // tier-1 tile bytes (32 codes, hi only)
#define NT2    64           // tier-2: 16-code tiles
#define TB2    16384        // tier-2 tile bytes (16 codes, hi+lo)
#define EPS1   0.3f
#define EPS2   8.0e-3f
#define TIE_TOL 3.5e-5
#define FLTMAX  3.402823466e+38f
// workspace layout (bytes)
#define WS_C2   0           // 4 KB
#define WS_CNT  4096        // int
#define WS_CNT2 4160        // int
#define WS_LST  8192        // 256 KB (65536 ints)
#define WS_LST2 270336      // 256 KB
#define WS_CBT1 532480      // 512 KB  (tier-1 hi-only tiles)
#define WS_CBT2 1056768     // 1 MB    (tier-2 hi+lo tiles)

typedef __attribute__((ext_vector_type(8))) short bf16x8;   // 4 VGPR
typedef __attribute__((ext_vector_type(4))) float f32x4;    // 4 VGPR

// float*s -> bf16 (RNE) hi + exact-residual lo
__device__ __forceinline__ void cvt8s(const float4& a, const float4& b, float s,
                                      bf16x8& h, bf16x8& l) {
    float f[8] = {a.x*s, a.y*s, a.z*s, a.w*s, b.x*s, b.y*s, b.z*s, b.w*s};
    #pragma unroll
    for (int e = 0; e < 8; ++e) {
        unsigned u  = __float_as_uint(f[e]);
        unsigned hr = u + 0x7FFFu + ((u >> 16) & 1u);
        unsigned short hs = (unsigned short)(hr >> 16);
        float hf = __uint_as_float((unsigned)hs << 16);
        float lo = f[e] - hf;                       // exact
        unsigned ul = __float_as_uint(lo);
        unsigned lr = ul + 0x7FFFu + ((ul >> 16) & 1u);
        h[e] = (short)hs;
        l[e] = (short)(lr >> 16);
    }
}

// lexicographic top-2 merge across lane groups {p, p+16, p+32, p+48}
__device__ __forceinline__ void merge16(float& tb1, int& ti1, float& tb2, int& ti2) {
    #pragma unroll
    for (int off = 16; off <= 32; off <<= 1) {
        float ob1 = __shfl_xor(tb1, off, 64);
        int   oi1 = __shfl_xor(ti1, off, 64);
        float ob2 = __shfl_xor(tb2, off, 64);
        int   oi2 = __shfl_xor(ti2, off, 64);
        float nb1, ca, cs2; int ni1, cai, csi;
        bool oless = (ob1 < tb1) || (ob1 == tb1 && oi1 < ti1);
        if (oless) { nb1 = ob1; ni1 = oi1; ca = tb1; cai = ti1; cs2 = ob2; csi = oi2; }
        else       { nb1 = tb1; ni1 = ti1; ca = ob1; cai = oi1; cs2 = tb2; csi = ti2; }
        if (cs2 < ca || (cs2 == ca && csi < cai)) { tb2 = cs2; ti2 = csi; }
        else                                      { tb2 = ca;  ti2 = cai; }
        tb1 = nb1; ti1 = ni1;
    }
}

// ---------- kernel P: counters + c2 (fp64) + both tile formats ----------
__global__ __launch_bounds__(256) void vq_prep_kernel(const float* __restrict__ cb,
                                                      char* __restrict__ ws) {
    float* c2f  = (float*)(ws + WS_C2);
    char*  cbt1 = ws + WS_CBT1;
    char*  cbt2 = ws + WS_CBT2;
    if (blockIdx.x == 0 && threadIdx.x == 0) {
        *(int*)(ws + WS_CNT)  = 0;
        *(int*)(ws + WS_CNT2) = 0;
    }
    const int chunk = blockIdx.x * 256 + threadIdx.x;    // [0, 32768)
    const int k = chunk >> 5;                            // code
    const int p = chunk & 31;                            // 8-dim chunk
    const float4* src = (const float4*)(cb + (size_t)k * DIMS + p * 8);
    float4 a = src[0], b = src[1];

    double s = (double)a.x*a.x + (double)a.y*a.y + (double)a.z*a.z + (double)a.w*a.w
             + (double)b.x*b.x + (double)b.y*b.y + (double)b.z*b.z + (double)b.w*b.w;
    #pragma unroll
    for (int off = 16; off > 0; off >>= 1) s += __shfl_xor(s, off, 64);
    if (p == 0) c2f[k] = (float)s;

    bf16x8 h, l;
    cvt8s(a, b, -2.0f, h, l);
    // tier-1 layout (32-code tiles, hi only):
    {
        const int t = k >> 5, g = (k >> 4) & 1, r = k & 15;
        const int soff = ((p >> 2) << 11) + (g << 10) + ((p & 3) << 8) + (r << 4);
        *(bf16x8*)(cbt1 + (size_t)t * TB1 + soff) = h;
    }
    // tier-2 layout (16-code tiles, hi+lo, R20-verbatim):
    {
        const int t = k >> 4, r = k & 15;
        const int soff = (p << 8) + (r << 4);            // p*256 + r*16
        *(bf16x8*)(cbt2 + (size_t)t * TB2 + soff)        = h;
        *(bf16x8*)(cbt2 + (size_t)t * TB2 + 8192 + soff) = l;
    }
}

__device__ __forceinline__ void stage4(const char* __restrict__ cbt, int t, int tb,
                                       char* dst, int w, int lane) {
    const char* src = cbt + (size_t)t * tb + w * 4096 + lane * 16;
    char* d = dst + w * 4096;
    #pragma unroll
    for (int i = 0; i < 4; ++i)
        __builtin_amdgcn_global_load_lds(
            (const __attribute__((address_space(1))) unsigned int*)(src + i * 1024),
            (__attribute__((address_space(3))) unsigned int*)(d + i * 1024),
            16, 0, 0);
}

// ---------- kernel T1: hi-only MFMA assign (R21-verbatim) ----------
__global__ __launch_bounds__(256, 4) void vq_assign_kernel(const float* __restrict__ x,
                                                           const float* __restrict__ cb,
                                                           char* __restrict__ ws,
                                                           float* __restrict__ out) {
    const char*  cbt = ws + WS_CBT1;
    const float* c2f = (const float*)(ws + WS_C2);
    int* cnt  = (int*)(ws + WS_CNT);
    int* list = (int*)(ws + WS_LST);

    __shared__ __attribute__((aligned(16))) char ldsbuf[2][TB1];

    const int tid  = threadIdx.x;
    const int lane = tid & 63;
    const int w    = tid >> 6;
    const int n0   = blockIdx.x * BMBLK;

    stage4(cbt, 0, TB1, ldsbuf[0], w, lane);

    bf16x8 xh[8], xl[8];
    {
        const float* xrow = x + (size_t)(n0 + w * 16 + (lane & 15)) * DIMS;
        const int ks = (lane >> 4) * 8;
        #pragma unroll
        for (int kc = 0; kc < 8; ++kc) {
            float4 a = *(const float4*)(xrow + kc * 32 + ks);
            float4 b = *(const float4*)(xrow + kc * 32 + ks + 4);
            cvt8s(a, b, 1.0f, xh[kc], xl[kc]);
        }
    }
    __syncthreads();

    float tb1 = FLTMAX, tb2 = FLTMAX;
    int   ti1 = 0,      ti2 = 0;

    const int r  = lane & 15;
    const int sl = lane >> 4;
    const int lanebase = sl * 256 + r * 16;

    for (int t = 0; t < NT1; ++t) {
        const int buf = t & 1;
        if (t + 1 < NT1)
            stage4(cbt, t + 1, TB1, ldsbuf[buf ^ 1], w, lane);

        const char* bh = &ldsbuf[buf][0];
        const int cb0 = t * 32 + sl * 4;
        float4 cs0 = *(const float4*)&c2f[cb0];
        float4 cs1 = *(const float4*)&c2f[cb0 + 16];
        f32x4 a0g0 = { cs0.x, cs0.y, cs0.z, cs0.w };
        f32x4 a1g0 = { 0.f, 0.f, 0.f, 0.f };
        f32x4 a0g1 = { cs1.x, cs1.y, cs1.z, cs1.w };
        f32x4 a1g1 = { 0.f, 0.f, 0.f, 0.f };

        #pragma unroll
        for (int kc = 0; kc < 8; ++kc) {
            const int byt = lanebase + kc * 2048;
            bf16x8 c0 = *(const bf16x8*)(bh + byt);
            bf16x8 c1 = *(const bf16x8*)(bh + byt + 1024);
            a0g0 = __builtin_amdgcn_mfma_f32_16x16x32_bf16(c0, xh[kc], a0g0, 0, 0, 0);
            a0g1 = __builtin_amdgcn_mfma_f32_16x16x32_bf16(c1, xh[kc], a0g1, 0, 0, 0);
            a1g0 = __builtin_amdgcn_mfma_f32_16x16x32_bf16(c0, xl[kc], a1g0, 0, 0, 0);
            a1g1 = __builtin_amdgcn_mfma_f32_16x16x32_bf16(c1, xl[kc], a1g1, 0, 0, 0);
        }

        #pragma unroll
        for (int j = 0; j < 4; ++j) {
            const int code = cb0 + j;
            float m = a0g0[j] + a1g0[j];
            if (m < tb1)      { tb2 = tb1; ti2 = ti1; tb1 = m; ti1 = code; }
            else if (m < tb2) { tb2 = m; ti2 = code; }
        }
        #pragma unroll
        for (int j = 0; j < 4; ++j) {
            const int code = cb0 + 16 + j;
            float m = a0g1[j] + a1g1[j];
            if (m < tb1)      { tb2 = tb1; ti2 = ti1; tb1 = m; ti1 = code; }
            else if (m < tb2) { tb2 = m; ti2 = code; }
        }
        __syncthreads();
    }

    merge16(tb1, ti1, tb2, ti2);

    if (lane < 16) {
        if (tb2 - tb1 < EPS1) {
            int pos = atomicAdd(cnt, 1);
            list[pos] = n0 + w * 16 + lane;
        }
    }

    #pragma unroll 4
    for (int p = 0; p < 16; ++p) {
        const int row = __shfl(ti1, p, 64);
        const float4* srcr = (const float4*)(cb + (size_t)row * DIMS);
        float4*       dstr = (float4*)(out + (size_t)(n0 + w * 16 + p) * DIMS);
        dstr[lane] = srcr[lane];
    }
}

// ---------- kernel T2: gathered 3-chain MFMA, GLOBAL-DIRECT (no LDS) ------
__global__ __launch_bounds__(256) void vq_refine2_kernel(const float* __restrict__ x,
                                                         const float* __restrict__ cb,
                                                         char* __restrict__ ws,
                                                         float* __restrict__ out) {
    const char*  cbt = ws + WS_CBT2;
    const float* c2f = (const float*)(ws + WS_C2);
    const int*   cnt  = (const int*)(ws + WS_CNT);
    const int*   list = (const int*)(ws + WS_LST);
    int*         cnt2 = (int*)(ws + WS_CNT2);
    int*         lst2 = (int*)(ws + WS_LST2);

    const int count = cnt[0];
    const int base  = blockIdx.x * BMBLK;
    if (base >= count) return;

    const int tid  = threadIdx.x;
    const int lane = tid & 63;
    const int w    = tid >> 6;

    const int eidx = base + w * 16 + (lane & 15);
    const int nidx = list[eidx < count ? eidx : base];

    bf16x8 xh[8], xl[8];
    {
        const float* xrow = x + (size_t)nidx * DIMS;
        const int ks = (lane >> 4) * 8;
        #pragma unroll
        for (int kc = 0; kc < 8; ++kc) {
            float4 a = *(const float4*)(xrow + kc * 32 + ks);
            float4 b = *(const float4*)(xrow + kc * 32 + ks + 4);
            cvt8s(a, b, 1.0f, xh[kc], xl[kc]);
        }
    }

    float tb1 = FLTMAX, tb2 = FLTMAX;
    int   ti1 = 0,      ti2 = 0;

    const int r  = lane & 15;
    const int sl = lane >> 4;
    const int lanebase = sl * 256 + r * 16;   // wave reads 1KB contiguous / kc

    for (int t = 0; t < NT2; ++t) {
        const char* tp = cbt + (size_t)t * TB2 + lanebase;

        const int cb0 = t * 16 + sl * 4;
        float4 cs = *(const float4*)&c2f[cb0];
        f32x4 a0 = { cs.x, cs.y, cs.z, cs.w };
        f32x4 a1 = { 0.f, 0.f, 0.f, 0.f };
        f32x4 a2 = { 0.f, 0.f, 0.f, 0.f };

        #pragma unroll
        for (int kc = 0; kc < 8; ++kc) {
            bf16x8 ch = *(const bf16x8*)(tp + kc * 1024);          // coalesced
            bf16x8 cl = *(const bf16x8*)(tp + 8192 + kc * 1024);   // coalesced
            a0 = __builtin_amdgcn_mfma_f32_16x16x32_bf16(ch, xh[kc], a0, 0, 0, 0);
            a1 = __builtin_amdgcn_mfma_f32_16x16x32_bf16(ch, xl[kc], a1, 0, 0, 0);
            a2 = __builtin_amdgcn_mfma_f32_16x16x32_bf16(cl, xh[kc], a2, 0, 0, 0);
        }

        #pragma unroll
        for (int j = 0; j < 4; ++j) {
            const int code = cb0 + j;
            float m = (a0[j] + a1[j]) + a2[j];
            if (m < tb1)      { tb2 = tb1; ti2 = ti1; tb1 = m; ti1 = code; }
            else if (m < tb2) { tb2 = m; ti2 = code; }
        }
    }

    merge16(tb1, ti1, tb2, ti2);

    if (lane < 16 && (base + w * 16 + lane) < count) {
        if (tb2 - tb1 < EPS2) {
            int pos = atomicAdd(cnt2, 1);
            lst2[pos] = nidx;
        }
    }

    // gather-write (dups benign: same value)
    #pragma unroll 4
    for (int p = 0; p < 16; ++p) {
        const int row = __shfl(ti1, p, 64);
        const int pn  = __shfl(nidx, p, 64);
        const float4* srcr = (const float4*)(cb + (size_t)row * DIMS);
        float4*       dstr = (float4*)(out + (size_t)pn * DIMS);
        dstr[lane] = srcr[lane];
    }
}

// ---------- kernel T3: fp64 ILP full scan (R19-verbatim, R6 tie rule) ------
__global__ __launch_bounds__(256) void vq_refine3_kernel(const float* __restrict__ x,
                                                         const float* __restrict__ cb,
                                                         char* __restrict__ ws,
                                                         float* __restrict__ out) {
    const int* cnt2 = (const int*)(ws + WS_CNT2);
    const int* lst2 = (const int*)(ws + WS_LST2);

    __shared__ double wd1[4], wd2[4];
    __shared__ int    wi1[4], wi2[4];
    __shared__ int    sel;

    const int tid  = threadIdx.x;
    const int lane = tid & 63;
    const int w    = tid >> 6;
    const int count = cnt2[0];

    for (int li = blockIdx.x; li < count; li += gridDim.x) {
        const int n = lst2[li];

        float4 xv = ((const float4*)(x + (size_t)n * DIMS))[lane];
        const double x0 = (double)xv.x, x1 = (double)xv.y;
        const double x2 = (double)xv.z, x3 = (double)xv.w;

        double b1 = 1.0e300, b2 = 1.0e300;
        int    i1 = 0,       i2 = 0;

        const int kw = w * 256;
        for (int kb = 0; kb < 256; kb += 8) {
            double s[8];
            #pragma unroll
            for (int u = 0; u < 8; ++u) {
                float4 cv = ((const float4*)(cb + (size_t)(kw + kb + u) * DIMS))[lane];
                double t0 = x0 - (double)cv.x;
                double t1 = x1 - (double)cv.y;
                double t2 = x2 - (double)cv.z;
                double t3 = x3 - (double)cv.w;
                s[u] = fma(t0, t0, fma(t1, t1, fma(t2, t2, t3 * t3)));
            }
            #pragma unroll
            for (int off = 32; off > 0; off >>= 1) {
                #pragma unroll
                for (int u = 0; u < 8; ++u)
                    s[u] += __shfl_xor(s[u], off, 64);
            }
            #pragma unroll
            for (int u = 0; u < 8; ++u) {
                const int k = kw + kb + u;
                if (s[u] < b1)      { b2 = b1; i2 = i1; b1 = s[u]; i1 = k; }
                else if (s[u] < b2) { b2 = s[u]; i2 = k; }
            }
        }

        if (lane == 0) { wd1[w] = b1; wi1[w] = i1; wd2[w] = b2; wi2[w] = i2; }
        __syncthreads();

        if (tid == 0) {
            double B1 = 1.0e300, B2 = 1.0e300;
            int    J1 = 0,       J2 = 0;
            #pragma unroll
            for (int g = 0; g < 4; ++g) {
                double v = wd1[g]; int ii = wi1[g];
                if (v < B1 || (v == B1 && ii < J1)) { B2 = B1; J2 = J1; B1 = v; J1 = ii; }
                else if (v < B2 || (v == B2 && ii < J2)) { B2 = v; J2 = ii; }
                v = wd2[g]; ii = wi2[g];
                if (v < B1 || (v == B1 && ii < J1)) { B2 = B1; J2 = J1; B1 = v; J1 = ii; }
                else if (v < B2 || (v == B2 && ii < J2)) { B2 = v; J2 = ii; }
            }
            sel = (B2 - B1 < TIE_TOL && J2 < J1) ? J2 : J1;
        }
        __syncthreads();

        const float4* cb4 = (const float4*)(cb + (size_t)sel * DIMS);
        float4*       o4  = (float4*)(out + (size_t)n * DIMS);
        if (tid < 64) o4[tid] = cb4[tid];
        __syncthreads();
    }
}

extern "C" void kernel_launch(void* const* d_in, const int* in_sizes, int n_in,
                              void* d_out, int out_size, void* d_ws, size_t ws_size,
                              hipStream_t stream) {
    const float* x  = (const float*)d_in[0];   // [16,4096,256]
    const float* cb = (const float*)d_in[1];   // [1024,256]
    float* out = (float*)d_out;                // [16,4096,256]
    char*  ws  = (char*)d_ws;

    vq_prep_kernel<<<128, 256, 0, stream>>>(cb, ws);
    vq_assign_kernel<<<NPTS / BMBLK, 256, 0, stream>>>(x, cb, ws, out);
    vq_refine2_kernel<<<NPTS / BMBLK, 256, 0, stream>>>(x, cb, ws, out);
    vq_refine3_kernel<<<512, 256, 0, stream>>>(x, cb, ws, out);
}

// Round 25
// 189.779 us; speedup vs baseline: 1.4932x; 1.4932x over previous
//
#include <hip/hip_runtime.h>

// VectorQuantizer: B=16, T=4096, D=256, K=1024 (fp32 in/out)
// N = B*T = 65536. out[n] = codebook[argmin_k ||x_n - c_k||^2]
//
// Three-tier cascade, every tier a previously-PASSED numeric config:
//   T1) hi-only bf16 MFMA assign (R21..R24-verbatim, ~86us): 32-code tiles,
//       contiguous layout, 0 conflicts. gap < 0.3 -> flag (~10k pts).
//   T2) gathered 3-chain bf16 MFMA re-assign (R20-verbatim numerics,
//       err sigma~1e-4). R25: block = 16 points, wave w scans codes
//       [w*256,(w+1)*256) global-direct (16 tiles, coalesced 1KB wave
//       loads), cross-wave lexicographic merge in LDS. (R24 lesson:
//       one wave scanning all 64 tiles at 1 block/CU = naked latency
//       chain, 143us; 4x shorter path + 4x TLP fixes it.)
//       gap < 8e-3 -> flag2 (~4 pts).
//   T3) fp64 ILP full scan (R19-verbatim) + tie rule "runner-up within
//       TIE_TOL=3.5e-5 and lower index wins" (round-6 verified).

#define DIMS   256
#define NCODE  1024
#define NPTS   65536
#define BMBLK  64           // T1: points per block (4 waves x 16)
#define NT1    32           // tier-1: 32-code tiles
#define TB1    16384        // tier-1 tile bytes (32 codes, hi only)
#define TB2    16384        // tier-2 tile bytes (16 codes, hi+lo)
#define EPS1   0.3f
#define EPS2   8.0e-3f
#define TIE_TOL 3.5e-5
#define FLTMAX  3.402823466e+38f
// workspace layout (bytes)
#define WS_C2   0           // 4 KB
#define WS_CNT  4096        // int
#define WS_CNT2 4160        // int
#define WS_LST  8192        // 256 KB (65536 ints)
#define WS_LST2 270336      // 256 KB
#define WS_CBT1 532480      // 512 KB  (tier-1 hi-only tiles)
#define WS_CBT2 1056768     // 1 MB    (tier-2 hi+lo tiles)

typedef __attribute__((ext_vector_type(8))) short bf16x8;   // 4 VGPR
typedef __attribute__((ext_vector_type(4))) float f32x4;    // 4 VGPR

// float*s -> bf16 (RNE) hi + exact-residual lo
__device__ __forceinline__ void cvt8s(const float4& a, const float4& b, float s,
                                      bf16x8& h, bf16x8& l) {
    float f[8] = {a.x*s, a.y*s, a.z*s, a.w*s, b.x*s, b.y*s, b.z*s, b.w*s};
    #pragma unroll
    for (int e = 0; e < 8; ++e) {
        unsigned u  = __float_as_uint(f[e]);
        unsigned hr = u + 0x7FFFu + ((u >> 16) & 1u);
        unsigned short hs = (unsigned short)(hr >> 16);
        float hf = __uint_as_float((unsigned)hs << 16);
        float lo = f[e] - hf;                       // exact
        unsigned ul = __float_as_uint(lo);
        unsigned lr = ul + 0x7FFFu + ((ul >> 16) & 1u);
        h[e] = (short)hs;
        l[e] = (short)(lr >> 16);
    }
}

// lexicographic top-2 merge across lane groups {p, p+16, p+32, p+48}
__device__ __forceinline__ void merge16(float& tb1, int& ti1, float& tb2, int& ti2) {
    #pragma unroll
    for (int off = 16; off <= 32; off <<= 1) {
        float ob1 = __shfl_xor(tb1, off, 64);
        int   oi1 = __shfl_xor(ti1, off, 64);
        float ob2 = __shfl_xor(tb2, off, 64);
        int   oi2 = __shfl_xor(ti2, off, 64);
        float nb1, ca, cs2; int ni1, cai, csi;
        bool oless = (ob1 < tb1) || (ob1 == tb1 && oi1 < ti1);
        if (oless) { nb1 = ob1; ni1 = oi1; ca = tb1; cai = ti1; cs2 = ob2; csi = oi2; }
        else       { nb1 = tb1; ni1 = ti1; ca = ob1; cai = oi1; cs2 = tb2; csi = ti2; }
        if (cs2 < ca || (cs2 == ca && csi < cai)) { tb2 = cs2; ti2 = csi; }
        else                                      { tb2 = ca;  ti2 = cai; }
        tb1 = nb1; ti1 = ni1;
    }
}

// ---------- kernel P: counters + c2 (fp64) + both tile formats ----------
__global__ __launch_bounds__(256) void vq_prep_kernel(const float* __restrict__ cb,
                                                      char* __restrict__ ws) {
    float* c2f  = (float*)(ws + WS_C2);
    char*  cbt1 = ws + WS_CBT1;
    char*  cbt2 = ws + WS_CBT2;
    if (blockIdx.x == 0 && threadIdx.x == 0) {
        *(int*)(ws + WS_CNT)  = 0;
        *(int*)(ws + WS_CNT2) = 0;
    }
    const int chunk = blockIdx.x * 256 + threadIdx.x;    // [0, 32768)
    const int k = chunk >> 5;                            // code
    const int p = chunk & 31;                            // 8-dim chunk
    const float4* src = (const float4*)(cb + (size_t)k * DIMS + p * 8);
    float4 a = src[0], b = src[1];

    double s = (double)a.x*a.x + (double)a.y*a.y + (double)a.z*a.z + (double)a.w*a.w
             + (double)b.x*b.x + (double)b.y*b.y + (double)b.z*b.z + (double)b.w*b.w;
    #pragma unroll
    for (int off = 16; off > 0; off >>= 1) s += __shfl_xor(s, off, 64);
    if (p == 0) c2f[k] = (float)s;

    bf16x8 h, l;
    cvt8s(a, b, -2.0f, h, l);
    // tier-1 layout (32-code tiles, hi only):
    {
        const int t = k >> 5, g = (k >> 4) & 1, r = k & 15;
        const int soff = ((p >> 2) << 11) + (g << 10) + ((p & 3) << 8) + (r << 4);
        *(bf16x8*)(cbt1 + (size_t)t * TB1 + soff) = h;
    }
    // tier-2 layout (16-code tiles, hi+lo, R20-verbatim):
    {
        const int t = k >> 4, r = k & 15;
        const int soff = (p << 8) + (r << 4);            // p*256 + r*16
        *(bf16x8*)(cbt2 + (size_t)t * TB2 + soff)        = h;
        *(bf16x8*)(cbt2 + (size_t)t * TB2 + 8192 + soff) = l;
    }
}

__device__ __forceinline__ void stage4(const char* __restrict__ cbt, int t, int tb,
                                       char* dst, int w, int lane) {
    const char* src = cbt + (size_t)t * tb + w * 4096 + lane * 16;
    char* d = dst + w * 4096;
    #pragma unroll
    for (int i = 0; i < 4; ++i)
        __builtin_amdgcn_global_load_lds(
            (const __attribute__((address_space(1))) unsigned int*)(src + i * 1024),
            (__attribute__((address_space(3))) unsigned int*)(d + i * 1024),
            16, 0, 0);
}

// ---------- kernel T1: hi-only MFMA assign (R21-verbatim) ----------
__global__ __launch_bounds__(256, 4) void vq_assign_kernel(const float* __restrict__ x,
                                                           const float* __restrict__ cb,
                                                           char* __restrict__ ws,
                                                           float* __restrict__ out) {
    const char*  cbt = ws + WS_CBT1;
    const float* c2f = (const float*)(ws + WS_C2);
    int* cnt  = (int*)(ws + WS_CNT);
    int* list = (int*)(ws + WS_LST);

    __shared__ __attribute__((aligned(16))) char ldsbuf[2][TB1];

    const int tid  = threadIdx.x;
    const int lane = tid & 63;
    const int w    = tid >> 6;
    const int n0   = blockIdx.x * BMBLK;

    stage4(cbt, 0, TB1, ldsbuf[0], w, lane);

    bf16x8 xh[8], xl[8];
    {
        const float* xrow = x + (size_t)(n0 + w * 16 + (lane & 15)) * DIMS;
        const int ks = (lane >> 4) * 8;
        #pragma unroll
        for (int kc = 0; kc < 8; ++kc) {
            float4 a = *(const float4*)(xrow + kc * 32 + ks);
            float4 b = *(const float4*)(xrow + kc * 32 + ks + 4);
            cvt8s(a, b, 1.0f, xh[kc], xl[kc]);
        }
    }
    __syncthreads();

    float tb1 = FLTMAX, tb2 = FLTMAX;
    int   ti1 = 0,      ti2 = 0;

    const int r  = lane & 15;
    const int sl = lane >> 4;
    const int lanebase = sl * 256 + r * 16;

    for (int t = 0; t < NT1; ++t) {
        const int buf = t & 1;
        if (t + 1 < NT1)
            stage4(cbt, t + 1, TB1, ldsbuf[buf ^ 1], w, lane);

        const char* bh = &ldsbuf[buf][0];
        const int cb0 = t * 32 + sl * 4;
        float4 cs0 = *(const float4*)&c2f[cb0];
        float4 cs1 = *(const float4*)&c2f[cb0 + 16];
        f32x4 a0g0 = { cs0.x, cs0.y, cs0.z, cs0.w };
        f32x4 a1g0 = { 0.f, 0.f, 0.f, 0.f };
        f32x4 a0g1 = { cs1.x, cs1.y, cs1.z, cs1.w };
        f32x4 a1g1 = { 0.f, 0.f, 0.f, 0.f };

        #pragma unroll
        for (int kc = 0; kc < 8; ++kc) {
            const int byt = lanebase + kc * 2048;
            bf16x8 c0 = *(const bf16x8*)(bh + byt);
            bf16x8 c1 = *(const bf16x8*)(bh + byt + 1024);
            a0g0 = __builtin_amdgcn_mfma_f32_16x16x32_bf16(c0, xh[kc], a0g0, 0, 0, 0);
            a0g1 = __builtin_amdgcn_mfma_f32_16x16x32_bf16(c1, xh[kc], a0g1, 0, 0, 0);
            a1g0 = __builtin_amdgcn_mfma_f32_16x16x32_bf16(c0, xl[kc], a1g0, 0, 0, 0);
            a1g1 = __builtin_amdgcn_mfma_f32_16x16x32_bf16(c1, xl[kc], a1g1, 0, 0, 0);
        }

        #pragma unroll
        for (int j = 0; j < 4; ++j) {
            const int code = cb0 + j;
            float m = a0g0[j] + a1g0[j];
            if (m < tb1)      { tb2 = tb1; ti2 = ti1; tb1 = m; ti1 = code; }
            else if (m < tb2) { tb2 = m; ti2 = code; }
        }
        #pragma unroll
        for (int j = 0; j < 4; ++j) {
            const int code = cb0 + 16 + j;
            float m = a0g1[j] + a1g1[j];
            if (m < tb1)      { tb2 = tb1; ti2 = ti1; tb1 = m; ti1 = code; }
            else if (m < tb2) { tb2 = m; ti2 = code; }
        }
        __syncthreads();
    }

    merge16(tb1, ti1, tb2, ti2);

    if (lane < 16) {
        if (tb2 - tb1 < EPS1) {
            int pos = atomicAdd(cnt, 1);
            list[pos] = n0 + w * 16 + lane;
        }
    }

    #pragma unroll 4
    for (int p = 0; p < 16; ++p) {
        const int row = __shfl(ti1, p, 64);
        const float4* srcr = (const float4*)(cb + (size_t)row * DIMS);
        float4*       dstr = (float4*)(out + (size_t)(n0 + w * 16 + p) * DIMS);
        dstr[lane] = srcr[lane];
    }
}

// ---------- kernel T2: 16 points/block, wave w scans codes [w*256,(w+1)*256) ----
__global__ __launch_bounds__(256) void vq_refine2_kernel(const float* __restrict__ x,
                                                         const float* __restrict__ cb,
                                                         char* __restrict__ ws,
                                                         float* __restrict__ out) {
    const char*  cbt = ws + WS_CBT2;
    const float* c2f = (const float*)(ws + WS_C2);
    const int*   cnt  = (const int*)(ws + WS_CNT);
    const int*   list = (const int*)(ws + WS_LST);
    int*         cnt2 = (int*)(ws + WS_CNT2);
    int*         lst2 = (int*)(ws + WS_LST2);

    const int count = cnt[0];
    const int base  = blockIdx.x * 16;
    if (base >= count) return;

    __shared__ float s_b1[4][16], s_b2[4][16];
    __shared__ int   s_i1[4][16], s_i2[4][16];
    __shared__ int   s_sel[16];
    __shared__ int   s_n[16];

    const int tid  = threadIdx.x;
    const int lane = tid & 63;
    const int w    = tid >> 6;

    const int eidx = base + (lane & 15);               // same 16 pts for all waves
    const int nidx = list[eidx < count ? eidx : base];
    if (tid < 16) s_n[tid] = list[(base + tid) < count ? (base + tid) : base];

    bf16x8 xh[8], xl[8];
    {
        const float* xrow = x + (size_t)nidx * DIMS;
        const int ks = (lane >> 4) * 8;
        #pragma unroll
        for (int kc = 0; kc < 8; ++kc) {
            float4 a = *(const float4*)(xrow + kc * 32 + ks);
            float4 b = *(const float4*)(xrow + kc * 32 + ks + 4);
            cvt8s(a, b, 1.0f, xh[kc], xl[kc]);
        }
    }

    float tb1 = FLTMAX, tb2 = FLTMAX;
    int   ti1 = 0,      ti2 = 0;

    const int r  = lane & 15;
    const int sl = lane >> 4;
    const int lanebase = sl * 256 + r * 16;   // wave reads 1KB contiguous / kc

    // wave w owns 16 tiles: global tile index w*16 + t, codes ascending
    for (int t = 0; t < 16; ++t) {
        const char* tp = cbt + (size_t)(w * 16 + t) * TB2 + lanebase;

        const int cb0 = w * 256 + t * 16 + sl * 4;
        float4 cs = *(const float4*)&c2f[cb0];
        f32x4 a0 = { cs.x, cs.y, cs.z, cs.w };
        f32x4 a1 = { 0.f, 0.f, 0.f, 0.f };
        f32x4 a2 = { 0.f, 0.f, 0.f, 0.f };

        #pragma unroll
        for (int kc = 0; kc < 8; ++kc) {
            bf16x8 ch = *(const bf16x8*)(tp + kc * 1024);          // coalesced
            bf16x8 cl = *(const bf16x8*)(tp + 8192 + kc * 1024);   // coalesced
            a0 = __builtin_amdgcn_mfma_f32_16x16x32_bf16(ch, xh[kc], a0, 0, 0, 0);
            a1 = __builtin_amdgcn_mfma_f32_16x16x32_bf16(ch, xl[kc], a1, 0, 0, 0);
            a2 = __builtin_amdgcn_mfma_f32_16x16x32_bf16(cl, xh[kc], a2, 0, 0, 0);
        }

        #pragma unroll
        for (int j = 0; j < 4; ++j) {
            const int code = cb0 + j;
            float m = (a0[j] + a1[j]) + a2[j];
            if (m < tb1)      { tb2 = tb1; ti2 = ti1; tb1 = m; ti1 = code; }
            else if (m < tb2) { tb2 = m; ti2 = code; }
        }
    }

    merge16(tb1, ti1, tb2, ti2);      // per-point top-2 over this wave's 256 codes

    if (lane < 16) {
        s_b1[w][lane] = tb1;  s_i1[w][lane] = ti1;
        s_b2[w][lane] = tb2;  s_i2[w][lane] = ti2;
    }
    __syncthreads();

    // cross-wave lexicographic merge + flag + select (one thread per point)
    if (tid < 16) {
        float B1 = FLTMAX, B2 = FLTMAX;
        int   J1 = 0,      J2 = 0;
        #pragma unroll
        for (int g = 0; g < 4; ++g) {
            float v = s_b1[g][tid]; int ii = s_i1[g][tid];
            if (v < B1 || (v == B1 && ii < J1)) { B2 = B1; J2 = J1; B1 = v; J1 = ii; }
            else if (v < B2 || (v == B2 && ii < J2)) { B2 = v; J2 = ii; }
            v = s_b2[g][tid]; ii = s_i2[g][tid];
            if (v < B1 || (v == B1 && ii < J1)) { B2 = B1; J2 = J1; B1 = v; J1 = ii; }
            else if (v < B2 || (v == B2 && ii < J2)) { B2 = v; J2 = ii; }
        }
        s_sel[tid] = J1;
        if ((base + tid) < count && (B2 - B1 < EPS2)) {
            int pos = atomicAdd(cnt2, 1);
            lst2[pos] = s_n[tid];
        }
    }
    __syncthreads();

    // write: wave w writes points w*4 .. w*4+3 (64 lanes x 16B = 1 row)
    #pragma unroll
    for (int q = 0; q < 4; ++q) {
        const int p = w * 4 + q;
        if ((base + p) < count) {
            const float4* srcr = (const float4*)(cb + (size_t)s_sel[p] * DIMS);
            float4*       dstr = (float4*)(out + (size_t)s_n[p] * DIMS);
            dstr[lane] = srcr[lane];
        }
    }
}

// ---------- kernel T3: fp64 ILP full scan (R19-verbatim, R6 tie rule) ------
__global__ __launch_bounds__(256) void vq_refine3_kernel(const float* __restrict__ x,
                                                         const float* __restrict__ cb,
                                                         char* __restrict__ ws,
                                                         float* __restrict__ out) {
    const int* cnt2 = (const int*)(ws + WS_CNT2);
    const int* lst2 = (const int*)(ws + WS_LST2);

    __shared__ double wd1[4], wd2[4];
    __shared__ int    wi1[4], wi2[4];
    __shared__ int    sel;

    const int tid  = threadIdx.x;
    const int lane = tid & 63;
    const int w    = tid >> 6;
    const int count = cnt2[0];

    for (int li = blockIdx.x; li < count; li += gridDim.x) {
        const int n = lst2[li];

        float4 xv = ((const float4*)(x + (size_t)n * DIMS))[lane];
        const double x0 = (double)xv.x, x1 = (double)xv.y;
        const double x2 = (double)xv.z, x3 = (double)xv.w;

        double b1 = 1.0e300, b2 = 1.0e300;
        int    i1 = 0,       i2 = 0;

        const int kw = w * 256;
        for (int kb = 0; kb < 256; kb += 8) {
            double s[8];
            #pragma unroll
            for (int u = 0; u < 8; ++u) {
                float4 cv = ((const float4*)(cb + (size_t)(kw + kb + u) * DIMS))[lane];
                double t0 = x0 - (double)cv.x;
                double t1 = x1 - (double)cv.y;
                double t2 = x2 - (double)cv.z;
                double t3 = x3 - (double)cv.w;
                s[u] = fma(t0, t0, fma(t1, t1, fma(t2, t2, t3 * t3)));
            }
            #pragma unroll
            for (int off = 32; off > 0; off >>= 1) {
                #pragma unroll
                for (int u = 0; u < 8; ++u)
                    s[u] += __shfl_xor(s[u], off, 64);
            }
            #pragma unroll
            for (int u = 0; u < 8; ++u) {
                const int k = kw + kb + u;
                if (s[u] < b1)      { b2 = b1; i2 = i1; b1 = s[u]; i1 = k; }
                else if (s[u] < b2) { b2 = s[u]; i2 = k; }
            }
        }

        if (lane == 0) { wd1[w] = b1; wi1[w] = i1; wd2[w] = b2; wi2[w] = i2; }
        __syncthreads();

        if (tid == 0) {
            double B1 = 1.0e300, B2 = 1.0e300;
            int    J1 = 0,       J2 = 0;
            #pragma unroll
            for (int g = 0; g < 4; ++g) {
                double v = wd1[g]; int ii = wi1[g];
                if (v < B1 || (v == B1 && ii < J1)) { B2 = B1; J2 = J1; B1 = v; J1 = ii; }
                else if (v < B2 || (v == B2 && ii < J2)) { B2 = v; J2 = ii; }
                v = wd2[g]; ii = wi2[g];
                if (v < B1 || (v == B1 && ii < J1)) { B2 = B1; J2 = J1; B1 = v; J1 = ii; }
                else if (v < B2 || (v == B2 && ii < J2)) { B2 = v; J2 = ii; }
            }
            sel = (B2 - B1 < TIE_TOL && J2 < J1) ? J2 : J1;
        }
        __syncthreads();

        const float4* cb4 = (const float4*)(cb + (size_t)sel * DIMS);
        float4*       o4  = (float4*)(out + (size_t)n * DIMS);
        if (tid < 64) o4[tid] = cb4[tid];
        __syncthreads();
    }
}

extern "C" void kernel_launch(void* const* d_in, const int* in_sizes, int n_in,
                              void* d_out, int out_size, void* d_ws, size_t ws_size,
                              hipStream_t stream) {
    const float* x  = (const float*)d_in[0];   // [16,4096,256]
    const float* cb = (const float*)d_in[1];   // [1024,256]
    float* out = (float*)d_out;                // [16,4096,256]
    char*  ws  = (char*)d_ws;

    vq_prep_kernel<<<128, 256, 0, stream>>>(cb, ws);
    vq_assign_kernel<<<NPTS / BMBLK, 256, 0, stream>>>(x, cb, ws, out);
    vq_refine2_kernel<<<NPTS / 16, 256, 0, stream>>>(x, cb, ws, out);
    vq_refine3_kernel<<<512, 256, 0, stream>>>(x, cb, ws, out);
}

// Round 26
// 186.565 us; speedup vs baseline: 1.5189x; 1.0172x over previous
//
#include <hip/hip_runtime.h>

// VectorQuantizer: B=16, T=4096, D=256, K=1024 (fp32 in/out)
// N = B*T = 65536. out[n] = codebook[argmin_k ||x_n - c_k||^2]
//
// Three-tier cascade (R26: fp16 replaces bf16 in T1/T2 -- 8x smaller
// quantization error -> 5x fewer flags; structures R25-verbatim):
//   T1) hi-only fp16 MFMA assign: 32-code tiles, contiguous layout,
//       0 conflicts. sigma~6e-3; gap < EPS1=0.06 (6.6 sigma) -> flag (~2k).
//   T2) gathered 3-chain fp16 MFMA re-assign, 16 pts/block, wave w scans
//       codes [w*256,(w+1)*256) global-direct. sigma~1e-4 (fp32-accum
//       dominated); gap < EPS2=8e-3 (R20-validated, 57 sigma) -> flag2.
//   T3) fp64 ILP full scan (R19-verbatim) + tie rule "runner-up within
//       TIE_TOL=3.5e-5 and lower index wins" (round-6 verified).

#define DIMS   256
#define NCODE  1024
#define NPTS   65536
#define BMBLK  64           // T1: points per block (4 waves x 16)
#define NT1    32           // tier-1: 32-code tiles
#define TB1    16384        // tier-1 tile bytes (32 codes, hi only)
#define TB2    16384        // tier-2 tile bytes (16 codes, hi+lo)
#define EPS1   0.06f
#define EPS2   8.0e-3f
#define TIE_TOL 3.5e-5
#define FLTMAX  3.402823466e+38f
// workspace layout (bytes)
#define WS_C2   0           // 4 KB
#define WS_CNT  4096        // int
#define WS_CNT2 4160        // int
#define WS_LST  8192        // 256 KB (65536 ints)
#define WS_LST2 270336      // 256 KB
#define WS_CBT1 532480      // 512 KB  (tier-1 hi-only tiles)
#define WS_CBT2 1056768     // 1 MB    (tier-2 hi+lo tiles)

typedef __attribute__((ext_vector_type(8))) _Float16 f16x8;  // 4 VGPR
typedef __attribute__((ext_vector_type(4))) float    f32x4;  // 4 VGPR

// float*s -> fp16 (RNE) hi + fp16 residual lo
__device__ __forceinline__ void cvt8s(const float4& a, const float4& b, float s,
                                      f16x8& h, f16x8& l) {
    float f[8] = {a.x*s, a.y*s, a.z*s, a.w*s, b.x*s, b.y*s, b.z*s, b.w*s};
    #pragma unroll
    for (int e = 0; e < 8; ++e) {
        _Float16 hh = (_Float16)f[e];
        float lo = f[e] - (float)hh;
        h[e] = hh;
        l[e] = (_Float16)lo;
    }
}

// lexicographic top-2 merge across lane groups {p, p+16, p+32, p+48}
__device__ __forceinline__ void merge16(float& tb1, int& ti1, float& tb2, int& ti2) {
    #pragma unroll
    for (int off = 16; off <= 32; off <<= 1) {
        float ob1 = __shfl_xor(tb1, off, 64);
        int   oi1 = __shfl_xor(ti1, off, 64);
        float ob2 = __shfl_xor(tb2, off, 64);
        int   oi2 = __shfl_xor(ti2, off, 64);
        float nb1, ca, cs2; int ni1, cai, csi;
        bool oless = (ob1 < tb1) || (ob1 == tb1 && oi1 < ti1);
        if (oless) { nb1 = ob1; ni1 = oi1; ca = tb1; cai = ti1; cs2 = ob2; csi = oi2; }
        else       { nb1 = tb1; ni1 = ti1; ca = ob1; cai = oi1; cs2 = tb2; csi = ti2; }
        if (cs2 < ca || (cs2 == ca && csi < cai)) { tb2 = cs2; ti2 = csi; }
        else                                      { tb2 = ca;  ti2 = cai; }
        tb1 = nb1; ti1 = ni1;
    }
}

// ---------- kernel P: counters + c2 (fp64) + both tile formats ----------
__global__ __launch_bounds__(256) void vq_prep_kernel(const float* __restrict__ cb,
                                                      char* __restrict__ ws) {
    float* c2f  = (float*)(ws + WS_C2);
    char*  cbt1 = ws + WS_CBT1;
    char*  cbt2 = ws + WS_CBT2;
    if (blockIdx.x == 0 && threadIdx.x == 0) {
        *(int*)(ws + WS_CNT)  = 0;
        *(int*)(ws + WS_CNT2) = 0;
    }
    const int chunk = blockIdx.x * 256 + threadIdx.x;    // [0, 32768)
    const int k = chunk >> 5;                            // code
    const int p = chunk & 31;                            // 8-dim chunk
    const float4* src = (const float4*)(cb + (size_t)k * DIMS + p * 8);
    float4 a = src[0], b = src[1];

    double s = (double)a.x*a.x + (double)a.y*a.y + (double)a.z*a.z + (double)a.w*a.w
             + (double)b.x*b.x + (double)b.y*b.y + (double)b.z*b.z + (double)b.w*b.w;
    #pragma unroll
    for (int off = 16; off > 0; off >>= 1) s += __shfl_xor(s, off, 64);
    if (p == 0) c2f[k] = (float)s;

    f16x8 h, l;
    cvt8s(a, b, -2.0f, h, l);
    // tier-1 layout (32-code tiles, hi only):
    {
        const int t = k >> 5, g = (k >> 4) & 1, r = k & 15;
        const int soff = ((p >> 2) << 11) + (g << 10) + ((p & 3) << 8) + (r << 4);
        *(f16x8*)(cbt1 + (size_t)t * TB1 + soff) = h;
    }
    // tier-2 layout (16-code tiles, hi+lo):
    {
        const int t = k >> 4, r = k & 15;
        const int soff = (p << 8) + (r << 4);            // p*256 + r*16
        *(f16x8*)(cbt2 + (size_t)t * TB2 + soff)        = h;
        *(f16x8*)(cbt2 + (size_t)t * TB2 + 8192 + soff) = l;
    }
}

__device__ __forceinline__ void stage4(const char* __restrict__ cbt, int t, int tb,
                                       char* dst, int w, int lane) {
    const char* src = cbt + (size_t)t * tb + w * 4096 + lane * 16;
    char* d = dst + w * 4096;
    #pragma unroll
    for (int i = 0; i < 4; ++i)
        __builtin_amdgcn_global_load_lds(
            (const __attribute__((address_space(1))) unsigned int*)(src + i * 1024),
            (__attribute__((address_space(3))) unsigned int*)(d + i * 1024),
            16, 0, 0);
}

// ---------- kernel T1: hi-only fp16 MFMA assign (R25 structure) ----------
__global__ __launch_bounds__(256, 4) void vq_assign_kernel(const float* __restrict__ x,
                                                           const float* __restrict__ cb,
                                                           char* __restrict__ ws,
                                                           float* __restrict__ out) {
    const char*  cbt = ws + WS_CBT1;
    const float* c2f = (const float*)(ws + WS_C2);
    int* cnt  = (int*)(ws + WS_CNT);
    int* list = (int*)(ws + WS_LST);

    __shared__ __attribute__((aligned(16))) char ldsbuf[2][TB1];

    const int tid  = threadIdx.x;
    const int lane = tid & 63;
    const int w    = tid >> 6;
    const int n0   = blockIdx.x * BMBLK;

    stage4(cbt, 0, TB1, ldsbuf[0], w, lane);

    f16x8 xh[8], xl[8];
    {
        const float* xrow = x + (size_t)(n0 + w * 16 + (lane & 15)) * DIMS;
        const int ks = (lane >> 4) * 8;
        #pragma unroll
        for (int kc = 0; kc < 8; ++kc) {
            float4 a = *(const float4*)(xrow + kc * 32 + ks);
            float4 b = *(const float4*)(xrow + kc * 32 + ks + 4);
            cvt8s(a, b, 1.0f, xh[kc], xl[kc]);
        }
    }
    __syncthreads();

    float tb1 = FLTMAX, tb2 = FLTMAX;
    int   ti1 = 0,      ti2 = 0;

    const int r  = lane & 15;
    const int sl = lane >> 4;
    const int lanebase = sl * 256 + r * 16;

    for (int t = 0; t < NT1; ++t) {
        const int buf = t & 1;
        if (t + 1 < NT1)
            stage4(cbt, t + 1, TB1, ldsbuf[buf ^ 1], w, lane);

        const char* bh = &ldsbuf[buf][0];
        const int cb0 = t * 32 + sl * 4;
        float4 cs0 = *(const float4*)&c2f[cb0];
        float4 cs1 = *(const float4*)&c2f[cb0 + 16];
        f32x4 a0g0 = { cs0.x, cs0.y, cs0.z, cs0.w };
        f32x4 a1g0 = { 0.f, 0.f, 0.f, 0.f };
        f32x4 a0g1 = { cs1.x, cs1.y, cs1.z, cs1.w };
        f32x4 a1g1 = { 0.f, 0.f, 0.f, 0.f };

        #pragma unroll
        for (int kc = 0; kc < 8; ++kc) {
            const int byt = lanebase + kc * 2048;
            f16x8 c0 = *(const f16x8*)(bh + byt);
            f16x8 c1 = *(const f16x8*)(bh + byt + 1024);
            a0g0 = __builtin_amdgcn_mfma_f32_16x16x32_f16(c0, xh[kc], a0g0, 0, 0, 0);
            a0g1 = __builtin_amdgcn_mfma_f32_16x16x32_f16(c1, xh[kc], a0g1, 0, 0, 0);
            a1g0 = __builtin_amdgcn_mfma_f32_16x16x32_f16(c0, xl[kc], a1g0, 0, 0, 0);
            a1g1 = __builtin_amdgcn_mfma_f32_16x16x32_f16(c1, xl[kc], a1g1, 0, 0, 0);
        }

        #pragma unroll
        for (int j = 0; j < 4; ++j) {
            const int code = cb0 + j;
            float m = a0g0[j] + a1g0[j];
            if (m < tb1)      { tb2 = tb1; ti2 = ti1; tb1 = m; ti1 = code; }
            else if (m < tb2) { tb2 = m; ti2 = code; }
        }
        #pragma unroll
        for (int j = 0; j < 4; ++j) {
            const int code = cb0 + 16 + j;
            float m = a0g1[j] + a1g1[j];
            if (m < tb1)      { tb2 = tb1; ti2 = ti1; tb1 = m; ti1 = code; }
            else if (m < tb2) { tb2 = m; ti2 = code; }
        }
        __syncthreads();
    }

    merge16(tb1, ti1, tb2, ti2);

    if (lane < 16) {
        if (tb2 - tb1 < EPS1) {
            int pos = atomicAdd(cnt, 1);
            list[pos] = n0 + w * 16 + lane;
        }
    }

    #pragma unroll 4
    for (int p = 0; p < 16; ++p) {
        const int row = __shfl(ti1, p, 64);
        const float4* srcr = (const float4*)(cb + (size_t)row * DIMS);
        float4*       dstr = (float4*)(out + (size_t)(n0 + w * 16 + p) * DIMS);
        dstr[lane] = srcr[lane];
    }
}

// ---------- kernel T2: 16 pts/block, wave w scans codes [w*256,(w+1)*256) ----
__global__ __launch_bounds__(256) void vq_refine2_kernel(const float* __restrict__ x,
                                                         const float* __restrict__ cb,
                                                         char* __restrict__ ws,
                                                         float* __restrict__ out) {
    const char*  cbt = ws + WS_CBT2;
    const float* c2f = (const float*)(ws + WS_C2);
    const int*   cnt  = (const int*)(ws + WS_CNT);
    const int*   list = (const int*)(ws + WS_LST);
    int*         cnt2 = (int*)(ws + WS_CNT2);
    int*         lst2 = (int*)(ws + WS_LST2);

    const int count = cnt[0];
    const int base  = blockIdx.x * 16;
    if (base >= count) return;

    __shared__ float s_b1[4][16], s_b2[4][16];
    __shared__ int   s_i1[4][16], s_i2[4][16];
    __shared__ int   s_sel[16];
    __shared__ int   s_n[16];

    const int tid  = threadIdx.x;
    const int lane = tid & 63;
    const int w    = tid >> 6;

    const int eidx = base + (lane & 15);               // same 16 pts for all waves
    const int nidx = list[eidx < count ? eidx : base];
    if (tid < 16) s_n[tid] = list[(base + tid) < count ? (base + tid) : base];

    f16x8 xh[8], xl[8];
    {
        const float* xrow = x + (size_t)nidx * DIMS;
        const int ks = (lane >> 4) * 8;
        #pragma unroll
        for (int kc = 0; kc < 8; ++kc) {
            float4 a = *(const float4*)(xrow + kc * 32 + ks);
            float4 b = *(const float4*)(xrow + kc * 32 + ks + 4);
            cvt8s(a, b, 1.0f, xh[kc], xl[kc]);
        }
    }

    float tb1 = FLTMAX, tb2 = FLTMAX;
    int   ti1 = 0,      ti2 = 0;

    const int r  = lane & 15;
    const int sl = lane >> 4;
    const int lanebase = sl * 256 + r * 16;   // wave reads 1KB contiguous / kc

    for (int t = 0; t < 16; ++t) {
        const char* tp = cbt + (size_t)(w * 16 + t) * TB2 + lanebase;

        const int cb0 = w * 256 + t * 16 + sl * 4;
        float4 cs = *(const float4*)&c2f[cb0];
        f32x4 a0 = { cs.x, cs.y, cs.z, cs.w };
        f32x4 a1 = { 0.f, 0.f, 0.f, 0.f };
        f32x4 a2 = { 0.f, 0.f, 0.f, 0.f };

        #pragma unroll
        for (int kc = 0; kc < 8; ++kc) {
            f16x8 ch = *(const f16x8*)(tp + kc * 1024);          // coalesced
            f16x8 cl = *(const f16x8*)(tp + 8192 + kc * 1024);   // coalesced
            a0 = __builtin_amdgcn_mfma_f32_16x16x32_f16(ch, xh[kc], a0, 0, 0, 0);
            a1 = __builtin_amdgcn_mfma_f32_16x16x32_f16(ch, xl[kc], a1, 0, 0, 0);
            a2 = __builtin_amdgcn_mfma_f32_16x16x32_f16(cl, xh[kc], a2, 0, 0, 0);
        }

        #pragma unroll
        for (int j = 0; j < 4; ++j) {
            const int code = cb0 + j;
            float m = (a0[j] + a1[j]) + a2[j];
            if (m < tb1)      { tb2 = tb1; ti2 = ti1; tb1 = m; ti1 = code; }
            else if (m < tb2) { tb2 = m; ti2 = code; }
        }
    }

    merge16(tb1, ti1, tb2, ti2);      // per-point top-2 over this wave's 256 codes

    if (lane < 16) {
        s_b1[w][lane] = tb1;  s_i1[w][lane] = ti1;
        s_b2[w][lane] = tb2;  s_i2[w][lane] = ti2;
    }
    __syncthreads();

    if (tid < 16) {
        float B1 = FLTMAX, B2 = FLTMAX;
        int   J1 = 0,      J2 = 0;
        #pragma unroll
        for (int g = 0; g < 4; ++g) {
            float v = s_b1[g][tid]; int ii = s_i1[g][tid];
            if (v < B1 || (v == B1 && ii < J1)) { B2 = B1; J2 = J1; B1 = v; J1 = ii; }
            else if (v < B2 || (v == B2 && ii < J2)) { B2 = v; J2 = ii; }
            v = s_b2[g][tid]; ii = s_i2[g][tid];
            if (v < B1 || (v == B1 && ii < J1)) { B2 = B1; J2 = J1; B1 = v; J1 = ii; }
            else if (v < B2 || (v == B2 && ii < J2)) { B2 = v; J2 = ii; }
        }
        s_sel[tid] = J1;
        if ((base + tid) < count && (B2 - B1 < EPS2)) {
            int pos = atomicAdd(cnt2, 1);
            lst2[pos] = s_n[tid];
        }
    }
    __syncthreads();

    #pragma unroll
    for (int q = 0; q < 4; ++q) {
        const int p = w * 4 + q;
        if ((base + p) < count) {
            const float4* srcr = (const float4*)(cb + (size_t)s_sel[p] * DIMS);
            float4*       dstr = (float4*)(out + (size_t)s_n[p] * DIMS);
            dstr[lane] = srcr[lane];
        }
    }
}

// ---------- kernel T3: fp64 ILP full scan (R19-verbatim, R6 tie rule) ------
__global__ __launch_bounds__(256) void vq_refine3_kernel(const float* __restrict__ x,
                                                         const float* __restrict__ cb,
                                                         char* __restrict__ ws,
                                                         float* __restrict__ out) {
    const int* cnt2 = (const int*)(ws + WS_CNT2);
    const int* lst2 = (const int*)(ws + WS_LST2);

    __shared__ double wd1[4], wd2[4];
    __shared__ int    wi1[4], wi2[4];
    __shared__ int    sel;

    const int tid  = threadIdx.x;
    const int lane = tid & 63;
    const int w    = tid >> 6;
    const int count = cnt2[0];

    for (int li = blockIdx.x; li < count; li += gridDim.x) {
        const int n = lst2[li];

        float4 xv = ((const float4*)(x + (size_t)n * DIMS))[lane];
        const double x0 = (double)xv.x, x1 = (double)xv.y;
        const double x2 = (double)xv.z, x3 = (double)xv.w;

        double b1 = 1.0e300, b2 = 1.0e300;
        int    i1 = 0,       i2 = 0;

        const int kw = w * 256;
        for (int kb = 0; kb < 256; kb += 8) {
            double s[8];
            #pragma unroll
            for (int u = 0; u < 8; ++u) {
                float4 cv = ((const float4*)(cb + (size_t)(kw + kb + u) * DIMS))[lane];
                double t0 = x0 - (double)cv.x;
                double t1 = x1 - (double)cv.y;
                double t2 = x2 - (double)cv.z;
                double t3 = x3 - (double)cv.w;
                s[u] = fma(t0, t0, fma(t1, t1, fma(t2, t2, t3 * t3)));
            }
            #pragma unroll
            for (int off = 32; off > 0; off >>= 1) {
                #pragma unroll
                for (int u = 0; u < 8; ++u)
                    s[u] += __shfl_xor(s[u], off, 64);
            }
            #pragma unroll
            for (int u = 0; u < 8; ++u) {
                const int k = kw + kb + u;
                if (s[u] < b1)      { b2 = b1; i2 = i1; b1 = s[u]; i1 = k; }
                else if (s[u] < b2) { b2 = s[u]; i2 = k; }
            }
        }

        if (lane == 0) { wd1[w] = b1; wi1[w] = i1; wd2[w] = b2; wi2[w] = i2; }
        __syncthreads();

        if (tid == 0) {
            double B1 = 1.0e300, B2 = 1.0e300;
            int    J1 = 0,       J2 = 0;
            #pragma unroll
            for (int g = 0; g < 4; ++g) {
                double v = wd1[g]; int ii = wi1[g];
                if (v < B1 || (v == B1 && ii < J1)) { B2 = B1; J2 = J1; B1 = v; J1 = ii; }
                else if (v < B2 || (v == B2 && ii < J2)) { B2 = v; J2 = ii; }
                v = wd2[g]; ii = wi2[g];
                if (v < B1 || (v == B1 && ii < J1)) { B2 = B1; J2 = J1; B1 = v; J1 = ii; }
                else if (v < B2 || (v == B2 && ii < J2)) { B2 = v; J2 = ii; }
            }
            sel = (B2 - B1 < TIE_TOL && J2 < J1) ? J2 : J1;
        }
        __syncthreads();

        const float4* cb4 = (const float4*)(cb + (size_t)sel * DIMS);
        float4*       o4  = (float4*)(out + (size_t)n * DIMS);
        if (tid < 64) o4[tid] = cb4[tid];
        __syncthreads();
    }
}

extern "C" void kernel_launch(void* const* d_in, const int* in_sizes, int n_in,
                              void* d_out, int out_size, void* d_ws, size_t ws_size,
                              hipStream_t stream) {
    const float* x  = (const float*)d_in[0];   // [16,4096,256]
    const float* cb = (const float*)d_in[1];   // [1024,256]
    float* out = (float*)d_out;                // [16,4096,256]
    char*  ws  = (char*)d_ws;

    vq_prep_kernel<<<128, 256, 0, stream>>>(cb, ws);
    vq_assign_kernel<<<NPTS / BMBLK, 256, 0, stream>>>(x, cb, ws, out);
    vq_refine2_kernel<<<NPTS / 16, 256, 0, stream>>>(x, cb, ws, out);
    vq_refine3_kernel<<<512, 256, 0, stream>>>(x, cb, ws, out);
}